// Round 4
// baseline (443.100 us; speedup 1.0000x reference)
//
#include <hip/hip_runtime.h>
#include <hip/hip_bf16.h>
#include <hip/hip_fp16.h>
#include <cmath>

// Problem constants
#define Bv   2
#define Tv   8
#define Hv   64
#define Wv   64
#define MPOS (Bv*Tv*Hv*Wv)           // 65536 positions
#define SCALEv 0.17677669529663687f  // 32^-0.5

// Attention tiling: 8x8 queries (one t, one b, one head) per block.
#define U_H   14
#define U_W   14
#define UPOS  588                    // 3*14*14 union K/V positions

// R4 attention LDS layout (bytes). 2-pass over u (u<320 / u>=320), K read
// DIRECTLY global->reg (no K LDS). Row stride 656 B = 164 dw == 4 (mod 32)
// -> 2-way (free) banking on b128 row-walks. Vt XOR-swizzled by (d>>3)<<5
// (8-row group = 5248 B, 128-aligned, bits5-6 clear -> bijective & in-group).
#define SVT    656                   // Vt/P row stride bytes
#define NCOL   328                   // row stride in ushorts
#define VTOFF  0                     // Vt: 32 x 656 B
#define POFF   20992                 // P : 64 x 656 B (f16 raw -> bf16 exp)
#define RPBOFF 62976                 // 845 f32 (this head's rpb)
#define INVOFF 66368                 // 64 f32 (1/sum)
#define SCROFF 66624                 // 8 waves x 64 lanes x 16 B AV partials
#define SMEM_BYTES 74816             // <= 81920 -> 2 blocks/CU (8 waves/SIMD)

// GEMM LDS row padding: 136 bf16 = 272 B; 272/4 = 68 dwords == 4 (mod 32)
#define KPAD 136

typedef __attribute__((ext_vector_type(8))) short bf16x8;   // MFMA A/B frag
typedef __attribute__((ext_vector_type(4))) float f32x4;    // MFMA C/D frag

__device__ __forceinline__ unsigned short f2bf16(float x) {
  return __builtin_bit_cast(unsigned short, __float2bfloat16(x));
}
__device__ __forceinline__ float bf2f(unsigned short h) {
  return __uint_as_float((unsigned)h << 16);
}
__device__ __forceinline__ float h2f(unsigned short h) {
  return __half2float(__builtin_bit_cast(__half, h));
}
__device__ __forceinline__ unsigned short f2h(float x) {
  return __builtin_bit_cast(unsigned short, __float2half(x));
}
__device__ __forceinline__ unsigned pk2(float a, float b) {
  return (unsigned)f2bf16(a) | ((unsigned)f2bf16(b) << 16);
}
// async global->LDS, 16B per lane; dest = wave-uniform base + lane*16
__device__ __forceinline__ void gload_lds16(const void* gsrc, void* ldst) {
  __builtin_amdgcn_global_load_lds(
      (const __attribute__((address_space(1))) unsigned int*)gsrc,
      (__attribute__((address_space(3))) unsigned int*)ldst, 16, 0, 0);
}

// ---------------------------------------------------------------------------
// Preconvert weights: transpose to [n][k] bf16 with KPAD row stride.
// proj_w additionally split hi/lo for the bf16x3 fp32-accurate GEMM.
// ---------------------------------------------------------------------------
__global__ __launch_bounds__(256) void preconvert(
    const float* __restrict__ qv_w, const float* __restrict__ k_w,
    const float* __restrict__ proj_w,
    ushort* __restrict__ wqvT, ushort* __restrict__ wkT,
    ushort* __restrict__ wpT_hi, ushort* __restrict__ wpT_lo) {
  const int id = blockIdx.x * 256 + threadIdx.x;
  if (id < 32768) {                       // qv: n<256, k<128
    const int n = id >> 7, kk = id & 127;
    wqvT[n * KPAD + kk] = f2bf16(qv_w[kk * 256 + n]);
  } else if (id < 49152) {                // k: n<128
    const int j = id - 32768;
    const int n = j >> 7, kk = j & 127;
    wkT[n * KPAD + kk] = f2bf16(k_w[kk * 128 + n]);
  } else {                                // proj: hi/lo split
    const int j = id - 49152;
    const int n = j >> 7, kk = j & 127;
    const float v = proj_w[kk * 128 + n];
    const unsigned short hi = f2bf16(v);
    wpT_hi[n * KPAD + kk] = hi;
    wpT_lo[n * KPAD + kk] = f2bf16(v - bf2f(hi));
  }
}

// ---------------------------------------------------------------------------
// Fused q/v/k projection GEMMs. Grid 1536 x 512thr; seg = bx>>9 (0=q,1=v,2=k).
// Each block: 128 rows x 128 cols. A-frags loaded DIRECTLY global->reg.
// ---------------------------------------------------------------------------
__global__ __launch_bounds__(512) void gemm_qvk(
    const float* __restrict__ x, const float* __restrict__ y,
    const ushort* __restrict__ wqvT, const ushort* __restrict__ wkT,
    const float* __restrict__ qv_b, const float* __restrict__ k_b,
    ushort* __restrict__ qbuf, ushort* __restrict__ vbuf,
    ushort* __restrict__ kbuf) {
  __shared__ ushort Ws[128 * KPAD];
  const int tid  = threadIdx.x;
  const int bx   = blockIdx.x;
  const int seg  = bx >> 9;                 // 0=q, 1=v, 2=k
  const int row0 = (bx & 511) * 128;

  const float*  A    = (seg == 2) ? y : x;
  const ushort* W    = (seg == 0) ? wqvT : (seg == 1) ? wqvT + 128 * KPAD : wkT;
  const float*  bias = (seg == 0) ? qv_b : (seg == 1) ? qv_b + 128 : k_b;
  ushort*       outp = (seg == 0) ? qbuf : (seg == 1) ? vbuf : kbuf;
  const float   scale = (seg == 0) ? SCALEv : 1.0f;

  // stage W async: 2176 uint4
  {
    const uint4* wg = (const uint4*)W;
    for (int i = tid; i < 2176; i += 512)
      gload_lds16(wg + i, (uint4*)Ws + i);
  }

  const int wv = tid >> 6, lane = tid & 63, quad = lane >> 4, l16 = lane & 15;
  const int arow = row0 + wv * 16 + l16;

  // A-frags direct to regs: 4 x 32B contiguous per lane
  bf16x8 af[4];
#pragma unroll
  for (int kk = 0; kk < 4; ++kk) {
    const float4* ap = (const float4*)(A + (size_t)arow * 128 + kk * 32 + quad * 8);
    const float4 a = ap[0], b2 = ap[1];
    af[kk] = __builtin_bit_cast(bf16x8,
        make_uint4(pk2(a.x, a.y), pk2(a.z, a.w), pk2(b2.x, b2.y), pk2(b2.z, b2.w)));
  }
  __syncthreads();

  f32x4 C[8];
#pragma unroll
  for (int nt = 0; nt < 8; ++nt) C[nt] = (f32x4){0.f, 0.f, 0.f, 0.f};

#pragma unroll
  for (int kk = 0; kk < 4; ++kk) {
#pragma unroll
    for (int nt = 0; nt < 8; ++nt) {
      const bf16x8 b2 = *(const bf16x8*)(Ws + (nt * 16 + l16) * KPAD + kk * 32 + quad * 8);
      C[nt] = __builtin_amdgcn_mfma_f32_16x16x32_bf16(af[kk], b2, C[nt], 0, 0, 0);
    }
  }

#pragma unroll
  for (int nt = 0; nt < 8; ++nt) {
    const int col = nt * 16 + l16;
    const float bv = bias[col];
#pragma unroll
    for (int r2 = 0; r2 < 4; ++r2) {
      const size_t row = row0 + wv * 16 + quad * 4 + r2;
      outp[row * 128 + col] = f2bf16((C[nt][r2] + bv) * scale);
    }
  }
}

// ---------------------------------------------------------------------------
// Output projection, bf16x3 (fp32-accurate). A hi/lo built in regs (no LDS);
// W hi/lo via gload_lds. 70 KB LDS -> 2 blocks/CU.
// ---------------------------------------------------------------------------
__global__ __launch_bounds__(512) void gemm_proj_mfma(
    const float* __restrict__ o, const ushort* __restrict__ wpT_hi,
    const ushort* __restrict__ wpT_lo, const float* __restrict__ proj_b,
    float* __restrict__ out) {
  __shared__ ushort Wh[128 * KPAD];
  __shared__ ushort Wl[128 * KPAD];
  const int tid  = threadIdx.x;
  const int row0 = blockIdx.x * 128;
  {
    const uint4* wgh = (const uint4*)wpT_hi;
    const uint4* wgl = (const uint4*)wpT_lo;
    for (int i = tid; i < 2176; i += 512) {
      gload_lds16(wgh + i, (uint4*)Wh + i);
      gload_lds16(wgl + i, (uint4*)Wl + i);
    }
  }

  const int wv = tid >> 6, lane = tid & 63, quad = lane >> 4, l16 = lane & 15;
  const int arow = row0 + wv * 16 + l16;

  bf16x8 ah[4], al[4];
#pragma unroll
  for (int kk = 0; kk < 4; ++kk) {
    const float4* ap = (const float4*)(o + (size_t)arow * 128 + kk * 32 + quad * 8);
    const float4 a = ap[0], b2 = ap[1];
    const float vs[8] = {a.x, a.y, a.z, a.w, b2.x, b2.y, b2.z, b2.w};
    unsigned hw[4], lw[4];
#pragma unroll
    for (int e = 0; e < 4; ++e) {
      const unsigned short h0 = f2bf16(vs[2 * e]);
      const unsigned short h1 = f2bf16(vs[2 * e + 1]);
      hw[e] = (unsigned)h0 | ((unsigned)h1 << 16);
      lw[e] = (unsigned)f2bf16(vs[2 * e] - bf2f(h0)) |
              ((unsigned)f2bf16(vs[2 * e + 1] - bf2f(h1)) << 16);
    }
    ah[kk] = __builtin_bit_cast(bf16x8, make_uint4(hw[0], hw[1], hw[2], hw[3]));
    al[kk] = __builtin_bit_cast(bf16x8, make_uint4(lw[0], lw[1], lw[2], lw[3]));
  }
  __syncthreads();

  f32x4 C[8];
#pragma unroll
  for (int nt = 0; nt < 8; ++nt) C[nt] = (f32x4){0.f, 0.f, 0.f, 0.f};

#pragma unroll
  for (int kk = 0; kk < 4; ++kk) {
#pragma unroll
    for (int nt = 0; nt < 8; ++nt) {
      const int boff = (nt * 16 + l16) * KPAD + kk * 32 + quad * 8;
      const bf16x8 bh = *(const bf16x8*)(Wh + boff);
      const bf16x8 bl = *(const bf16x8*)(Wl + boff);
      C[nt] = __builtin_amdgcn_mfma_f32_16x16x32_bf16(ah[kk], bh, C[nt], 0, 0, 0);
      C[nt] = __builtin_amdgcn_mfma_f32_16x16x32_bf16(ah[kk], bl, C[nt], 0, 0, 0);
      C[nt] = __builtin_amdgcn_mfma_f32_16x16x32_bf16(al[kk], bh, C[nt], 0, 0, 0);
    }
  }

#pragma unroll
  for (int nt = 0; nt < 8; ++nt) {
    const int col = nt * 16 + l16;
    const float bv = proj_b[col];
#pragma unroll
    for (int r2 = 0; r2 < 4; ++r2) {
      const size_t row = row0 + wv * 16 + quad * 4 + r2;
      out[row * 128 + col] = C[nt][r2] + bv;
    }
  }
}

// ---------------------------------------------------------------------------
// MFMA NA3D attention (union-GEMM). Block = 8x8 query tile (one b,t,head).
// R4: 2-pass over u, no K LDS (direct global B-frags), 74.8 KB LDS ->
// 2 blocks/CU (8 waves/SIMD). Softmax sums + AV accumulate across passes;
// normalization in the epilogue.
// ---------------------------------------------------------------------------
__global__ __launch_bounds__(1024, 8)
void na3d_tile(
    const ushort* __restrict__ qin,
    const ushort* __restrict__ kin,
    const ushort* __restrict__ vin,
    const float* __restrict__ rpb,
    float* __restrict__ oout) {
  __shared__ __align__(16) unsigned char smem[SMEM_BYTES];

  const int tid  = threadIdx.x;
  const int wv   = tid >> 6;          // 0..15
  const int lane = tid & 63;
  const int quad = lane >> 4;
  const int l16  = lane & 15;

  const int bx   = blockIdx.x;
  const int head = bx & 3;
  const int tile = bx >> 2;
  const int w0 = (tile & 7) << 3;
  const int h0 = ((tile >> 3) & 7) << 3;
  const int t  = (tile >> 6) & 7;
  const int b  = tile >> 9;

  const int st  = min(max(t - 1, 0), Tv - 3);
  const int u_h = min(max(h0 - 3, 0), Hv - U_H);
  const int u_w = min(max(w0 - 3, 0), Wv - U_W);
  const int rt_b = st - t + 2;   // 0..2

  // Q A-frag (held across both passes)
  const int mtile = wv & 3;
  bf16x8 afrag;
  {
    const int q_a  = mtile * 16 + l16;
    const int qh_a = h0 + (q_a >> 3), qw_a = w0 + (q_a & 7);
    const size_t qpos_a = ((size_t)(b * Tv + t) * Hv + qh_a) * Wv + qw_a;
    afrag = *(const bf16x8*)(qin + qpos_a * 128 + head * 32 + quad * 8);
  }
  // rpb -> LDS (read before first barrier of pass 0)
  if (tid < 845) ((float*)(smem + RPBOFF))[tid] = rpb[head * 845 + tid];

  // Softmax segment geometry (pass-invariant). 21 segments of 7 per query.
  const int qs = tid >> 4, l16s = tid & 15;
  const int qh_s = h0 + (qs >> 3), qw_s = w0 + (qs & 7);
  const int sh_s = min(max(qh_s - 3, 0), Hv - 7);
  const int sw_s = min(max(qw_s - 3, 0), Wv - 7);
  const int dh_s = sh_s - u_h, dw_s = sw_s - u_w;          // [0,7]
  const int rh0 = sh_s - qh_s + 6, rw0 = sw_s - qw_s + 6;  // [0,6]
  const int utA = l16s / 7, aA = l16s - utA * 7;
  const int u0A = utA * 196 + (dh_s + aA) * 14 + dw_s;
  const int bA  = (rt_b + utA) * 169 + (rh0 + aA) * 13 + rw0;
  const bool hasB = (l16s < 5);
  const int aB  = l16s + 2;
  const int u0B = 392 + (dh_s + aB) * 14 + dw_s;
  const int bB  = (rt_b + 2) * 169 + (rh0 + aB) * 13 + rw0;

  // AV wave mapping (pass-invariant)
  const int khalf = wv >> 3, mtA = (wv >> 1) & 3, ntA = wv & 1;
  const int dcol = ntA * 16 + l16;
  const unsigned vsw = ((unsigned)(dcol >> 3) & 3u) << 5;

  f32x4 o = {0.f, 0.f, 0.f, 0.f};
  float sum = 0.f;

#pragma unroll 1
  for (int pass = 0; pass < 2; ++pass) {
    const int lo   = pass ? 320 : 0;
    const int nu   = pass ? 288 : 320;    // u's consumed by AV this pass
    const int NT   = pass ? 18  : 20;     // QK u-tiles
    const int nval = pass ? 268 : 320;    // valid staged V positions

    // ---- V: issue global loads (latency hides under QK) ----
    uint4 vv[2];
    const int nchunk = nval * 4;
#pragma unroll
    for (int it = 0; it < 2; ++it) {
      const int j = tid + it * 1024;
      if (j < nchunk) {
        const int pos = lo + (j >> 2), c = j & 3;
        const int ta = pos / 196;
        const int r  = pos - ta * 196;
        const int rh = r / 14;
        const int ha = u_h + rh;
        const int wa = u_w + (r - rh * 14);
        const size_t gpos = (((size_t)(b * Tv + st + ta) * Hv + ha) * Wv + wa);
        vv[it] = ((const uint4*)vin)[gpos * 16 + head * 4 + c];
      }
    }

    // ---- QK: K B-frags DIRECT from global (L2), raw f16 scores -> P ----
    {
      ushort* ph = (ushort*)(smem + POFF);
      for (int nt = (wv >> 2); nt < NT; nt += 4) {
        const int u = lo + nt * 16 + l16;
        const int pos = min(u, UPOS - 1);        // clamp; garbage zeroed later
        const int ta = pos / 196;
        const int r  = pos - ta * 196;
        const int rh = r / 14;
        const int ha = u_h + rh;
        const int wa = u_w + (r - rh * 14);
        const size_t gpos = (((size_t)(b * Tv + st + ta) * Hv + ha) * Wv + wa);
        const bf16x8 bfrag = *(const bf16x8*)(kin + gpos * 128 + head * 32 + quad * 8);
        f32x4 c = {0.f, 0.f, 0.f, 0.f};
        c = __builtin_amdgcn_mfma_f32_16x16x32_bf16(afrag, bfrag, c, 0, 0, 0);
#pragma unroll
        for (int r2 = 0; r2 < 4; ++r2) {
          const int qrow = mtile * 16 + quad * 4 + r2;
          ph[qrow * NCOL + (u - lo)] = f2h(c[r2]);
        }
      }
    }

    // ---- V repack -> Vt (XOR-swizzled by (d>>3)<<5) ----
#pragma unroll
    for (int it = 0; it < 2; ++it) {
      const int j = tid + it * 1024;
      if (j < nchunk) {
        const int pos2 = j >> 2, c = j & 3;
        const unsigned sw = (unsigned)c << 5;       // d>>3 == c for this chunk
        const unsigned v4[4] = {vv[it].x, vv[it].y, vv[it].z, vv[it].w};
#pragma unroll
        for (int m2 = 0; m2 < 4; ++m2) {
          const int d0 = 8 * c + 2 * m2;
          const unsigned base = (unsigned)d0 * SVT + (unsigned)pos2 * 2;
          *(ushort*)(smem + VTOFF + (base ^ sw))         = (ushort)(v4[m2] & 0xffffu);
          *(ushort*)(smem + VTOFF + ((base + SVT) ^ sw)) = (ushort)(v4[m2] >> 16);
        }
      }
    }
    // Vt tail zero (pass1: u_local 268..287, 32 d x 10 dwords)
    if (pass == 1 && tid < 320) {
      const int d = tid / 10, jj = tid - d * 10;
      const unsigned base = (unsigned)d * SVT + 536u + (unsigned)jj * 4;
      *(unsigned*)(smem + VTOFF + (base ^ (((unsigned)d >> 3) << 5))) = 0u;
    }
    __syncthreads();   // (1) P raw + Vt complete

    // ---- softmax: read valid scores in this pass's range, exp, pack ----
    unsigned pkA[4] = {0u, 0u, 0u, 0u}, pkB[4] = {0u, 0u, 0u, 0u};
    {
      const ushort* Ps = (const ushort*)(smem + POFF) + qs * NCOL;
      const float* rpb_l = (const float*)(smem + RPBOFF);
      const int hi = lo + nu;
#pragma unroll
      for (int e = 0; e < 7; ++e) {
        const int u = u0A + e;
        if (u >= lo && u < hi) {
          const float s = h2f(Ps[u - lo]) + rpb_l[bA + e];
          const float ex = __expf(s);
          sum += ex;
          pkA[e >> 1] |= (unsigned)f2bf16(ex) << ((e & 1) * 16);
        }
      }
      if (hasB) {
#pragma unroll
        for (int e = 0; e < 7; ++e) {
          const int u = u0B + e;
          if (u >= lo && u < hi) {
            const float s = h2f(Ps[u - lo]) + rpb_l[bB + e];
            const float ex = __expf(s);
            sum += ex;
            pkB[e >> 1] |= (unsigned)f2bf16(ex) << ((e & 1) * 16);
          }
        }
      }
      if (pass == 1) {
        float sm = sum;
        sm += __shfl_xor(sm, 1);
        sm += __shfl_xor(sm, 2);
        sm += __shfl_xor(sm, 4);
        sm += __shfl_xor(sm, 8);
        if (l16s == 0) ((float*)(smem + INVOFF))[qs] = 1.0f / sm;
      }
    }
    __syncthreads();   // (2) raw reads done

    // ---- zero P wholesale (41 uint4/row) ----
    {
      uint4* Pv = (uint4*)(smem + POFF + (size_t)qs * SVT);
      for (int c = l16s; c < 41; c += 16) Pv[c] = make_uint4(0u, 0u, 0u, 0u);
    }
    __syncthreads();   // (3) zeros done

    // ---- scatter valid exps (bf16) ----
    {
      ushort* Pr = (ushort*)(smem + POFF) + qs * NCOL;
      const int hi = lo + nu;
#pragma unroll
      for (int e = 0; e < 7; ++e) {
        const int u = u0A + e;
        if (u >= lo && u < hi)
          Pr[u - lo] = (ushort)(pkA[e >> 1] >> ((e & 1) * 16));
      }
      if (hasB) {
#pragma unroll
        for (int e = 0; e < 7; ++e) {
          const int u = u0B + e;
          if (u >= lo && u < hi)
            Pr[u - lo] = (ushort)(pkB[e >> 1] >> ((e & 1) * 16));
        }
      }
    }
    __syncthreads();   // (4) P ready

    // ---- AV: kt-split across wave halves, accumulate across passes ----
    {
      const int ktn = pass ? 9 : 10;
      const int kt0 = khalf * 5;
      const int kt1 = khalf ? ktn : 5;
      const unsigned char* Abase = smem + POFF + (size_t)(mtA * 16 + l16) * SVT;
      const unsigned vlocal = (unsigned)dcol * SVT;
      for (int kt = kt0; kt < kt1; ++kt) {
        const bf16x8 a  = *(const bf16x8*)(Abase + kt * 64 + quad * 16);
        const bf16x8 bb = *(const bf16x8*)(smem + VTOFF +
                            ((vlocal + kt * 64 + quad * 16) ^ vsw));
        o = __builtin_amdgcn_mfma_f32_16x16x32_bf16(a, bb, o, 0, 0, 0);
      }
    }
    if (pass == 0) __syncthreads();   // (5) AV reads done -> restage
  }

  // ---- epilogue: combine khalves, normalize, store ----
  {
    f32x4* part = (f32x4*)(smem + SCROFF);
    if (khalf) part[(wv & 7) * 64 + lane] = o;
    __syncthreads();
    if (!khalf) {
      const f32x4 p2 = part[wv * 64 + lane];
      const float* invArr = (const float*)(smem + INVOFF);
#pragma unroll
      for (int r2 = 0; r2 < 4; ++r2) {
        const int qrow = mtA * 16 + quad * 4 + r2;
        const float val = (o[r2] + p2[r2]) * invArr[qrow];
        const int qh2 = h0 + (qrow >> 3), qw2 = w0 + (qrow & 7);
        const size_t qp2 = ((size_t)(b * Tv + t) * Hv + qh2) * Wv + qw2;
        oout[qp2 * 128 + head * 32 + dcol] = val;
      }
    }
  }
}

// ---------------------------------------------------------------------------
extern "C" void kernel_launch(void* const* d_in, const int* in_sizes, int n_in,
                              void* d_out, int out_size, void* d_ws, size_t ws_size,
                              hipStream_t stream) {
  const float* x      = (const float*)d_in[0];
  const float* y      = (const float*)d_in[1];
  const float* qv_w   = (const float*)d_in[2];
  const float* qv_b   = (const float*)d_in[3];
  const float* k_w    = (const float*)d_in[4];
  const float* k_b    = (const float*)d_in[5];
  const float* proj_w = (const float*)d_in[6];
  const float* proj_b = (const float*)d_in[7];
  const float* rpb    = (const float*)d_in[8];
  float* out = (float*)d_out;

  const size_t elems = (size_t)MPOS * 128;        // 8,388,608
  ushort* qbuf = (ushort*)d_ws;                   // 16.8 MB (bf16, SCALE folded)
  ushort* kbuf = qbuf + elems;                    // 16.8 MB
  ushort* vbuf = kbuf + elems;                    // 16.8 MB
  float*  obuf = (float*)(vbuf + elems);          // 33.5 MB (attn out fp32)
  ushort* wqvT   = (ushort*)(obuf + elems);
  ushort* wkT    = wqvT + 256 * KPAD;
  ushort* wpT_hi = wkT + 128 * KPAD;
  ushort* wpT_lo = wpT_hi + 128 * KPAD;

  preconvert    <<<256,  256, 0, stream>>>(qv_w, k_w, proj_w, wqvT, wkT, wpT_hi, wpT_lo);
  gemm_qvk      <<<1536, 512, 0, stream>>>(x, y, wqvT, wkT, qv_b, k_b, qbuf, vbuf, kbuf);
  na3d_tile     <<<4096, 1024, 0, stream>>>(qbuf, kbuf, vbuf, rpb, obuf);
  gemm_proj_mfma<<<512,  512, 0, stream>>>(obuf, wpT_hi, wpT_lo, proj_b, out);
}

// Round 5
// 258.208 us; speedup vs baseline: 1.7161x; 1.7161x over previous
//
#include <hip/hip_runtime.h>
#include <hip/hip_bf16.h>
#include <hip/hip_fp16.h>
#include <cmath>

// Problem constants
#define Bv   2
#define Tv   8
#define Hv   64
#define Wv   64
#define MPOS (Bv*Tv*Hv*Wv)           // 65536 positions
#define SCALEv 0.17677669529663687f  // 32^-0.5

// Attention tiling: 8x8 queries (one t, one b, one head) per block.
// R5: 3 passes, one per time-slice ut. 196 spatial union positions per pass,
// padded to 208 (QK tiles) / 224 (AV k-dim). K staged via global_load_lds.
#define SPOS  196                    // 14x14 spatial union per time slice
#define SVT   464                    // Vt/P row stride bytes (116 dw == 20 mod 32)
#define NCOLS 232                    // row stride in ushorts

// LDS layout (bytes)
#define KOFF   0                     // K: 208 slots x 64 B (13 x 1KB chunks)
#define VTOFF  13312                 // Vt: 32 x 464 B, XOR-swizzled (d>>3)<<5
#define POFF   28160                 // P : 64 x 464 B (f16 raw -> bf16 exp)
#define RPBOFF 57856                 // 845 f32 (this head's rpb)
#define INVOFF 61248                 // 64 f32 (1/sum)
#define SCROFF 61504                 // 8 waves x 64 lanes x 16 B AV partials
#define SMEM_BYTES 69696             // <= 81920 -> 2 blocks/CU (8 waves/SIMD)

// GEMM LDS row padding: 136 bf16 = 272 B; 272/4 = 68 dwords == 4 (mod 32)
#define KPAD 136

typedef __attribute__((ext_vector_type(8))) short bf16x8;   // MFMA A/B frag
typedef __attribute__((ext_vector_type(4))) float f32x4;    // MFMA C/D frag

__device__ __forceinline__ unsigned short f2bf16(float x) {
  return __builtin_bit_cast(unsigned short, __float2bfloat16(x));
}
__device__ __forceinline__ float bf2f(unsigned short h) {
  return __uint_as_float((unsigned)h << 16);
}
__device__ __forceinline__ float h2f(unsigned short h) {
  return __half2float(__builtin_bit_cast(__half, h));
}
__device__ __forceinline__ unsigned short f2h(float x) {
  return __builtin_bit_cast(unsigned short, __float2half(x));
}
__device__ __forceinline__ unsigned pk2(float a, float b) {
  return (unsigned)f2bf16(a) | ((unsigned)f2bf16(b) << 16);
}
// async global->LDS, 16B per lane; dest = wave-uniform base + lane*16
__device__ __forceinline__ void gload_lds16(const void* gsrc, void* ldst) {
  __builtin_amdgcn_global_load_lds(
      (const __attribute__((address_space(1))) unsigned int*)gsrc,
      (__attribute__((address_space(3))) unsigned int*)ldst, 16, 0, 0);
}

// ---------------------------------------------------------------------------
// Preconvert weights: transpose to [n][k] bf16 with KPAD row stride.
// ---------------------------------------------------------------------------
__global__ __launch_bounds__(256) void preconvert(
    const float* __restrict__ qv_w, const float* __restrict__ k_w,
    const float* __restrict__ proj_w,
    ushort* __restrict__ wqvT, ushort* __restrict__ wkT,
    ushort* __restrict__ wpT_hi, ushort* __restrict__ wpT_lo) {
  const int id = blockIdx.x * 256 + threadIdx.x;
  if (id < 32768) {                       // qv: n<256, k<128
    const int n = id >> 7, kk = id & 127;
    wqvT[n * KPAD + kk] = f2bf16(qv_w[kk * 256 + n]);
  } else if (id < 49152) {                // k: n<128
    const int j = id - 32768;
    const int n = j >> 7, kk = j & 127;
    wkT[n * KPAD + kk] = f2bf16(k_w[kk * 128 + n]);
  } else {                                // proj: hi/lo split
    const int j = id - 49152;
    const int n = j >> 7, kk = j & 127;
    const float v = proj_w[kk * 128 + n];
    const unsigned short hi = f2bf16(v);
    wpT_hi[n * KPAD + kk] = hi;
    wpT_lo[n * KPAD + kk] = f2bf16(v - bf2f(hi));
  }
}

// ---------------------------------------------------------------------------
// Fused q/v/k projection GEMMs. Grid 1536 x 512thr; seg = bx>>9 (0=q,1=v,2=k).
// ---------------------------------------------------------------------------
__global__ __launch_bounds__(512) void gemm_qvk(
    const float* __restrict__ x, const float* __restrict__ y,
    const ushort* __restrict__ wqvT, const ushort* __restrict__ wkT,
    const float* __restrict__ qv_b, const float* __restrict__ k_b,
    ushort* __restrict__ qbuf, ushort* __restrict__ vbuf,
    ushort* __restrict__ kbuf) {
  __shared__ ushort Ws[128 * KPAD];
  const int tid  = threadIdx.x;
  const int bx   = blockIdx.x;
  const int seg  = bx >> 9;                 // 0=q, 1=v, 2=k
  const int row0 = (bx & 511) * 128;

  const float*  A    = (seg == 2) ? y : x;
  const ushort* W    = (seg == 0) ? wqvT : (seg == 1) ? wqvT + 128 * KPAD : wkT;
  const float*  bias = (seg == 0) ? qv_b : (seg == 1) ? qv_b + 128 : k_b;
  ushort*       outp = (seg == 0) ? qbuf : (seg == 1) ? vbuf : kbuf;
  const float   scale = (seg == 0) ? SCALEv : 1.0f;

  {
    const uint4* wg = (const uint4*)W;
    for (int i = tid; i < 2176; i += 512)
      gload_lds16(wg + i, (uint4*)Ws + i);
  }

  const int wv = tid >> 6, lane = tid & 63, quad = lane >> 4, l16 = lane & 15;
  const int arow = row0 + wv * 16 + l16;

  bf16x8 af[4];
#pragma unroll
  for (int kk = 0; kk < 4; ++kk) {
    const float4* ap = (const float4*)(A + (size_t)arow * 128 + kk * 32 + quad * 8);
    const float4 a = ap[0], b2 = ap[1];
    af[kk] = __builtin_bit_cast(bf16x8,
        make_uint4(pk2(a.x, a.y), pk2(a.z, a.w), pk2(b2.x, b2.y), pk2(b2.z, b2.w)));
  }
  __syncthreads();

  f32x4 C[8];
#pragma unroll
  for (int nt = 0; nt < 8; ++nt) C[nt] = (f32x4){0.f, 0.f, 0.f, 0.f};

#pragma unroll
  for (int kk = 0; kk < 4; ++kk) {
#pragma unroll
    for (int nt = 0; nt < 8; ++nt) {
      const bf16x8 b2 = *(const bf16x8*)(Ws + (nt * 16 + l16) * KPAD + kk * 32 + quad * 8);
      C[nt] = __builtin_amdgcn_mfma_f32_16x16x32_bf16(af[kk], b2, C[nt], 0, 0, 0);
    }
  }

#pragma unroll
  for (int nt = 0; nt < 8; ++nt) {
    const int col = nt * 16 + l16;
    const float bv = bias[col];
#pragma unroll
    for (int r2 = 0; r2 < 4; ++r2) {
      const size_t row = row0 + wv * 16 + quad * 4 + r2;
      outp[row * 128 + col] = f2bf16((C[nt][r2] + bv) * scale);
    }
  }
}

// ---------------------------------------------------------------------------
// Output projection, bf16x3 (fp32-accurate).
// ---------------------------------------------------------------------------
__global__ __launch_bounds__(512) void gemm_proj_mfma(
    const float* __restrict__ o, const ushort* __restrict__ wpT_hi,
    const ushort* __restrict__ wpT_lo, const float* __restrict__ proj_b,
    float* __restrict__ out) {
  __shared__ ushort Wh[128 * KPAD];
  __shared__ ushort Wl[128 * KPAD];
  const int tid  = threadIdx.x;
  const int row0 = blockIdx.x * 128;
  {
    const uint4* wgh = (const uint4*)wpT_hi;
    const uint4* wgl = (const uint4*)wpT_lo;
    for (int i = tid; i < 2176; i += 512) {
      gload_lds16(wgh + i, (uint4*)Wh + i);
      gload_lds16(wgl + i, (uint4*)Wl + i);
    }
  }

  const int wv = tid >> 6, lane = tid & 63, quad = lane >> 4, l16 = lane & 15;
  const int arow = row0 + wv * 16 + l16;

  bf16x8 ah[4], al[4];
#pragma unroll
  for (int kk = 0; kk < 4; ++kk) {
    const float4* ap = (const float4*)(o + (size_t)arow * 128 + kk * 32 + quad * 8);
    const float4 a = ap[0], b2 = ap[1];
    const float vs[8] = {a.x, a.y, a.z, a.w, b2.x, b2.y, b2.z, b2.w};
    unsigned hw[4], lw[4];
#pragma unroll
    for (int e = 0; e < 4; ++e) {
      const unsigned short h0 = f2bf16(vs[2 * e]);
      const unsigned short h1 = f2bf16(vs[2 * e + 1]);
      hw[e] = (unsigned)h0 | ((unsigned)h1 << 16);
      lw[e] = (unsigned)f2bf16(vs[2 * e] - bf2f(h0)) |
              ((unsigned)f2bf16(vs[2 * e + 1] - bf2f(h1)) << 16);
    }
    ah[kk] = __builtin_bit_cast(bf16x8, make_uint4(hw[0], hw[1], hw[2], hw[3]));
    al[kk] = __builtin_bit_cast(bf16x8, make_uint4(lw[0], lw[1], lw[2], lw[3]));
  }
  __syncthreads();

  f32x4 C[8];
#pragma unroll
  for (int nt = 0; nt < 8; ++nt) C[nt] = (f32x4){0.f, 0.f, 0.f, 0.f};

#pragma unroll
  for (int kk = 0; kk < 4; ++kk) {
#pragma unroll
    for (int nt = 0; nt < 8; ++nt) {
      const int boff = (nt * 16 + l16) * KPAD + kk * 32 + quad * 8;
      const bf16x8 bh = *(const bf16x8*)(Wh + boff);
      const bf16x8 bl = *(const bf16x8*)(Wl + boff);
      C[nt] = __builtin_amdgcn_mfma_f32_16x16x32_bf16(ah[kk], bh, C[nt], 0, 0, 0);
      C[nt] = __builtin_amdgcn_mfma_f32_16x16x32_bf16(ah[kk], bl, C[nt], 0, 0, 0);
      C[nt] = __builtin_amdgcn_mfma_f32_16x16x32_bf16(al[kk], bh, C[nt], 0, 0, 0);
    }
  }

#pragma unroll
  for (int nt = 0; nt < 8; ++nt) {
    const int col = nt * 16 + l16;
    const float bv = proj_b[col];
#pragma unroll
    for (int r2 = 0; r2 < 4; ++r2) {
      const size_t row = row0 + wv * 16 + quad * 4 + r2;
      out[row * 128 + col] = C[nt][r2] + bv;
    }
  }
}

// ---------------------------------------------------------------------------
// MFMA NA3D attention. Block = 8x8 query tile (one b,t,head), 1024 thr.
// R5: 3 passes (one per ut), K via global_load_lds, 69.7 KB LDS ->
// 2 blocks/CU. Softmax zero/scatter are wave-local (no intra barriers).
// ---------------------------------------------------------------------------
__global__ __launch_bounds__(1024, 8)
void na3d_tile(
    const ushort* __restrict__ qin,
    const ushort* __restrict__ kin,
    const ushort* __restrict__ vin,
    const float* __restrict__ rpb,
    float* __restrict__ oout) {
  __shared__ __align__(16) unsigned char smem[SMEM_BYTES];

  const int tid  = threadIdx.x;
  const int wv   = tid >> 6;          // 0..15
  const int lane = tid & 63;
  const int quad = lane >> 4;
  const int l16  = lane & 15;

  const int bx   = blockIdx.x;
  const int head = bx & 3;
  const int tile = bx >> 2;
  const int w0 = (tile & 7) << 3;
  const int h0 = ((tile >> 3) & 7) << 3;
  const int t  = (tile >> 6) & 7;
  const int b  = tile >> 9;

  const int st  = min(max(t - 1, 0), Tv - 3);
  const int u_h = min(max(h0 - 3, 0), Hv - 14);
  const int u_w = min(max(w0 - 3, 0), Wv - 14);
  const int rt_b = st - t + 2;   // 0..2

  // Q A-frag (pass-invariant)
  const int mtile = wv & 3;
  bf16x8 afrag;
  {
    const int q_a  = mtile * 16 + l16;
    const int qh_a = h0 + (q_a >> 3), qw_a = w0 + (q_a & 7);
    const size_t qpos_a = ((size_t)(b * Tv + t) * Hv + qh_a) * Wv + qw_a;
    afrag = *(const bf16x8*)(qin + qpos_a * 128 + head * 32 + quad * 8);
  }
  // rpb -> LDS
  if (tid < 845) ((float*)(smem + RPBOFF))[tid] = rpb[head * 845 + tid];

  // softmax geometry (pass-invariant)
  const int qs = tid >> 4, l16s = tid & 15;
  const int qh_s = h0 + (qs >> 3), qw_s = w0 + (qs & 7);
  const int sh_s = min(max(qh_s - 3, 0), Hv - 7);
  const int sw_s = min(max(qw_s - 3, 0), Wv - 7);
  const int dh_s = sh_s - u_h, dw_s = sw_s - u_w;          // [0,7]
  const int rh0 = sh_s - qh_s + 6, rw0 = sw_s - qw_s + 6;  // [0,6]

  // AV wave mapping (pass-invariant)
  const int khalf = wv >> 3, mtA = (wv >> 1) & 3, ntA = wv & 1;
  const int dcol = ntA * 16 + l16;
  const unsigned vsw = ((unsigned)(dcol >> 3) & 3u) << 5;

  // V/K position decode for staging (thread-invariant across passes)
  const int vpos = tid >> 2, vc = tid & 3;       // V: tid<784
  const int vrh = vpos / 14, vrw = vpos - vrh * 14;
  const size_t vsp = ((size_t)(u_h + vrh) * Wv + (u_w + vrw)) * 16 + head * 4 + vc;
  // K: wave wv<13 stages chunk wv
  const int km = wv * 64 + lane;
  const int kpos0 = min(km >> 2, SPOS - 1);
  const int kslot = km & 3;
  const int kc = (kslot - (kpos0 >> 2)) & 3;
  const int krh = kpos0 / 14, krw = kpos0 - krh * 14;
  const size_t ksp = ((size_t)(u_h + krh) * Wv + (u_w + krw)) * 16 + head * 4 + kc;

  f32x4 o = {0.f, 0.f, 0.f, 0.f};
  float sum = 0.f;
  uint4 vv;

  // prologue: issue V + K for pass 0
  {
    const size_t tbase = (size_t)(b * Tv + st) * Hv * Wv * 16;
    if (tid < SPOS * 4) vv = ((const uint4*)vin)[tbase + vsp];
    if (wv < 13)
      gload_lds16((const uint4*)kin + tbase + ksp,
                  smem + KOFF + wv * 1024 + lane * 16);
  }

#pragma unroll 1
  for (int pass = 0; pass < 3; ++pass) {
    // ---- V repack -> Vt (XOR-swizzled) ----
    if (tid < SPOS * 4) {
      const unsigned sw = (unsigned)vc << 5;     // d>>3 == vc for this chunk
      const unsigned v4[4] = {vv.x, vv.y, vv.z, vv.w};
#pragma unroll
      for (int m2 = 0; m2 < 4; ++m2) {
        const int d0 = 8 * vc + 2 * m2;
        const unsigned base = (unsigned)d0 * SVT + (unsigned)vpos * 2;
        *(ushort*)(smem + VTOFF + (base ^ sw))         = (ushort)(v4[m2] & 0xffffu);
        *(ushort*)(smem + VTOFF + ((base + SVT) ^ sw)) = (ushort)(v4[m2] >> 16);
      }
    }
    // Vt tail zero: cols 196..231 (18 dwords x 32 rows), pass 0 only
    if (pass == 0 && tid < 576) {
      const int d = tid / 18, jj = tid - d * 18;
      const unsigned base = (unsigned)d * SVT + 392u + (unsigned)jj * 4;
      *(unsigned*)(smem + VTOFF + (base ^ (((unsigned)d >> 3) << 5))) = 0u;
    }
    __syncthreads();   // (A) K + Vt ready (vmcnt drained by barrier)

    // ---- QK: 13 tiles over 4 wave-groups, raw f16 scores -> P ----
    {
      ushort* ph = (ushort*)(smem + POFF);
      for (int nt = (wv >> 2); nt < 13; nt += 4) {
        const int u = nt * 16 + l16;
        const int slot = (quad + (u >> 2)) & 3;
        const bf16x8 bfrag = *(const bf16x8*)(smem + KOFF + u * 64 + slot * 16);
        f32x4 c = {0.f, 0.f, 0.f, 0.f};
        c = __builtin_amdgcn_mfma_f32_16x16x32_bf16(afrag, bfrag, c, 0, 0, 0);
#pragma unroll
        for (int r2 = 0; r2 < 4; ++r2) {
          const int qrow = mtile * 16 + quad * 4 + r2;
          ph[qrow * NCOLS + u] = f2h(c[r2]);
        }
      }
    }
    __syncthreads();   // (B) P raw ready

    // ---- softmax: 49 valid / query (7 runs of 7), read+exp -> zero -> scatter
    // All P[qs][*] accesses by qs's own 16-lane group -> wave-ordered, no
    // intra-phase barriers.
    {
      const ushort* Ps = (const ushort*)(smem + POFF) + qs * NCOLS;
      const float* rpb_l = (const float*)(smem + RPBOFF) + (rt_b + pass) * 169;
      float ex[4];
      int uu[4];
#pragma unroll
      for (int k = 0; k < 4; ++k) {
        const int e = l16s + 16 * k;
        const int a = (e * 37) >> 8;             // e/7 for e<64
        const int bb = e - 7 * a;
        uu[k] = (dh_s + a) * 14 + dw_s + bb;
        if (e < 49) {
          const float s = h2f(Ps[uu[k]]) + rpb_l[(rh0 + a) * 13 + rw0 + bb];
          ex[k] = __expf(s);
          sum += ex[k];
        }
      }
      if (pass == 2) {
        float sm = sum;
        sm += __shfl_xor(sm, 1);
        sm += __shfl_xor(sm, 2);
        sm += __shfl_xor(sm, 4);
        sm += __shfl_xor(sm, 8);
        if (l16s == 0) ((float*)(smem + INVOFF))[qs] = 1.0f / sm;
      }
      __builtin_amdgcn_sched_barrier(0);         // reads before zeros
      // zero row (29 uint4 = 232 cols)
      {
        uint4* Pv = (uint4*)(smem + POFF + (size_t)qs * SVT);
        Pv[l16s] = make_uint4(0u, 0u, 0u, 0u);
        if (l16s < 13) Pv[l16s + 16] = make_uint4(0u, 0u, 0u, 0u);
      }
      __builtin_amdgcn_sched_barrier(0);         // zeros before scatter
      // scatter valid exps
      ushort* Pr = (ushort*)(smem + POFF) + qs * NCOLS;
#pragma unroll
      for (int k = 0; k < 4; ++k) {
        const int e = l16s + 16 * k;
        if (e < 49) Pr[uu[k]] = f2bf16(ex[k]);
      }
    }
    __syncthreads();   // (E) P ready

    // ---- issue next pass's V + K (drains at barrier F, hidden by AV) ----
    if (pass < 2) {
      const size_t tbase = (size_t)(b * Tv + st + pass + 1) * Hv * Wv * 16;
      if (tid < SPOS * 4) vv = ((const uint4*)vin)[tbase + vsp];
      if (wv < 13)
        gload_lds16((const uint4*)kin + tbase + ksp,
                    smem + KOFF + wv * 1024 + lane * 16);
    }

    // ---- AV: 7 kts split across wave halves, accumulate across passes ----
    {
      const unsigned char* Abase = smem + POFF + (size_t)(mtA * 16 + l16) * SVT;
      const unsigned vlocal = (unsigned)dcol * SVT;
      const int kt0 = khalf ? 4 : 0;
      const int kt1 = khalf ? 7 : 4;
      for (int kt = kt0; kt < kt1; ++kt) {
        const bf16x8 a  = *(const bf16x8*)(Abase + kt * 64 + quad * 16);
        const bf16x8 bb = *(const bf16x8*)(smem + VTOFF +
                            ((vlocal + kt * 64 + quad * 16) ^ vsw));
        o = __builtin_amdgcn_mfma_f32_16x16x32_bf16(a, bb, o, 0, 0, 0);
      }
    }
    if (pass < 2) __syncthreads();   // (F) AV reads done -> restage Vt/K/P
  }

  // ---- epilogue: combine khalves, normalize, store ----
  {
    f32x4* part = (f32x4*)(smem + SCROFF);
    if (khalf) part[(wv & 7) * 64 + lane] = o;
    __syncthreads();
    if (!khalf) {
      const f32x4 p2 = part[wv * 64 + lane];
      const float* invArr = (const float*)(smem + INVOFF);
#pragma unroll
      for (int r2 = 0; r2 < 4; ++r2) {
        const int qrow = mtA * 16 + quad * 4 + r2;
        const float val = (o[r2] + p2[r2]) * invArr[qrow];
        const int qh2 = h0 + (qrow >> 3), qw2 = w0 + (qrow & 7);
        const size_t qp2 = ((size_t)(b * Tv + t) * Hv + qh2) * Wv + qw2;
        oout[qp2 * 128 + head * 32 + dcol] = val;
      }
    }
  }
}

// ---------------------------------------------------------------------------
extern "C" void kernel_launch(void* const* d_in, const int* in_sizes, int n_in,
                              void* d_out, int out_size, void* d_ws, size_t ws_size,
                              hipStream_t stream) {
  const float* x      = (const float*)d_in[0];
  const float* y      = (const float*)d_in[1];
  const float* qv_w   = (const float*)d_in[2];
  const float* qv_b   = (const float*)d_in[3];
  const float* k_w    = (const float*)d_in[4];
  const float* k_b    = (const float*)d_in[5];
  const float* proj_w = (const float*)d_in[6];
  const float* proj_b = (const float*)d_in[7];
  const float* rpb    = (const float*)d_in[8];
  float* out = (float*)d_out;

  const size_t elems = (size_t)MPOS * 128;        // 8,388,608
  ushort* qbuf = (ushort*)d_ws;                   // 16.8 MB (bf16, SCALE folded)
  ushort* kbuf = qbuf + elems;                    // 16.8 MB
  ushort* vbuf = kbuf + elems;                    // 16.8 MB
  float*  obuf = (float*)(vbuf + elems);          // 33.5 MB (attn out fp32)
  ushort* wqvT   = (ushort*)(obuf + elems);
  ushort* wkT    = wqvT + 256 * KPAD;
  ushort* wpT_hi = wkT + 128 * KPAD;
  ushort* wpT_lo = wpT_hi + 128 * KPAD;

  preconvert    <<<256,  256, 0, stream>>>(qv_w, k_w, proj_w, wqvT, wkT, wpT_hi, wpT_lo);
  gemm_qvk      <<<1536, 512, 0, stream>>>(x, y, wqvT, wkT, qv_b, k_b, qbuf, vbuf, kbuf);
  na3d_tile     <<<4096, 1024, 0, stream>>>(qbuf, kbuf, vbuf, rpb, obuf);
  gemm_proj_mfma<<<512,  512, 0, stream>>>(obuf, wpT_hi, wpT_lo, proj_b, out);
}